// Round 1
// baseline (1051.807 us; speedup 1.0000x reference)
//
#include <hip/hip_runtime.h>

#define THREADS 256

static __device__ __forceinline__ int imax(int a, int b){ return a > b ? a : b; }
static __device__ __forceinline__ int imin(int a, int b){ return a < b ? a : b; }

// ---------------- CSR build ----------------

__global__ void k_zero(int* __restrict__ p, int n){
    int i = blockIdx.x * blockDim.x + threadIdx.x;
    if (i < n) p[i] = 0;
}

__global__ void k_hist(const int* __restrict__ es, const int* __restrict__ ed,
                       int* __restrict__ cu, int* __restrict__ cc, int E){
    for (int e = blockIdx.x * blockDim.x + threadIdx.x; e < E; e += gridDim.x * blockDim.x){
        atomicAdd(&cu[es[e]], 1);
        atomicAdd(&cc[ed[e]], 1);
    }
}

// single-block exclusive scan; cnt_in may alias off/cur (per-index owner read-before-write)
__global__ void k_scan_small(const int* __restrict__ cnt_in, int* __restrict__ off,
                             int* __restrict__ cur, int n){
    __shared__ int ssum[THREADS];
    int t = threadIdx.x;
    int chunk = (n + THREADS - 1) / THREADS;
    int lo = t * chunk, hi = imin(lo + chunk, n);
    int s = 0;
    for (int i = lo; i < hi; i++) s += cnt_in[i];
    ssum[t] = s; __syncthreads();
    for (int d = 1; d < THREADS; d <<= 1){
        int v = (t >= d) ? ssum[t - d] : 0;
        __syncthreads();
        if (t >= d) ssum[t] += v;
        __syncthreads();
    }
    int base = t ? ssum[t - 1] : 0;
    for (int i = lo; i < hi; i++){
        int c = cnt_in[i];
        off[i] = base; cur[i] = base;
        base += c;
    }
    if (t == THREADS - 1) off[n] = base;
}

__global__ void k_scan1(const int* __restrict__ cnt, int* __restrict__ bsum, int n){
    __shared__ int red[THREADS];
    int t = threadIdx.x;
    int base = blockIdx.x * 2048;
    int s = 0;
    #pragma unroll
    for (int k = 0; k < 8; k++){ int i = base + t * 8 + k; if (i < n) s += cnt[i]; }
    red[t] = s; __syncthreads();
    for (int d = THREADS >> 1; d > 0; d >>= 1){
        if (t < d) red[t] += red[t + d];
        __syncthreads();
    }
    if (t == 0) bsum[blockIdx.x] = red[0];
}

__global__ void k_scan3(const int* __restrict__ cnt, const int* __restrict__ bsum,
                        int* __restrict__ off, int* __restrict__ cur, int n, int total){
    __shared__ int red[THREADS];
    int t = threadIdx.x;
    int base0 = blockIdx.x * 2048;
    int loc[8]; int s = 0;
    #pragma unroll
    for (int k = 0; k < 8; k++){ int i = base0 + t * 8 + k; loc[k] = (i < n) ? cnt[i] : 0; s += loc[k]; }
    red[t] = s; __syncthreads();
    for (int d = 1; d < THREADS; d <<= 1){
        int v = (t >= d) ? red[t - d] : 0;
        __syncthreads();
        if (t >= d) red[t] += v;
        __syncthreads();
    }
    int run = bsum[blockIdx.x] + (t ? red[t - 1] : 0);
    #pragma unroll
    for (int k = 0; k < 8; k++){
        int i = base0 + t * 8 + k;
        if (i < n){ off[i] = run; cur[i] = run; run += loc[k]; }
    }
    if (blockIdx.x == 0 && t == 0) off[n] = total;
}

__global__ void k_scatter(const int* __restrict__ es, const int* __restrict__ ed,
                          int* __restrict__ cur_c, int* __restrict__ cur_u,
                          int* __restrict__ csr_c, int* __restrict__ csr_u, int E){
    for (int e = blockIdx.x * blockDim.x + threadIdx.x; e < E; e += gridDim.x * blockDim.x){
        int s = es[e], d = ed[e];
        csr_c[atomicAdd(&cur_c[d], 1)] = s;   // per course: list of src users
        csr_u[atomicAdd(&cur_u[s], 1)] = d;   // per user:   list of dst courses
    }
}

// ---------------- feature fusion (courses only; xu computed on the fly) ----------------

__global__ void k_xc(const float* __restrict__ cx, const float* __restrict__ cemb,
                     const int* __restrict__ cidx, const float* __restrict__ Wc,
                     const float* __restrict__ bc, float* __restrict__ xc, int NC){
    int i = blockIdx.x * blockDim.x + threadIdx.x;
    if (i >= NC * 32) return;
    int c = i >> 5, f = i & 31;
    float v;
    if (f < 16) v = cemb[cidx[c] * 16 + f];
    else { int o = f - 16; v = bc[o] + cx[c * 2 + 0] * Wc[o * 2 + 0] + cx[c * 2 + 1] * Wc[o * 2 + 1]; }
    xc[i] = v;
}

// ---------------- layer 1 course side: agg(xu) -> hc -> {hc@c2r_Wl.T, hc@c2e_Wr.T} ----------------

__global__ __launch_bounds__(256) void k_course_l1(
    const int* __restrict__ off_c, const int* __restrict__ csr_c,
    const float* __restrict__ uemb, const int* __restrict__ uidx,
    const float* __restrict__ ux, const float* __restrict__ Wu, const float* __restrict__ bu,
    const float* __restrict__ Wl, const float* __restrict__ bl, const float* __restrict__ Wr,
    const float* __restrict__ Acoef /*c2r_Wl*/, const float* __restrict__ Bcoef /*c2e_Wr*/,
    const float* __restrict__ xc,
    float* __restrict__ hc2r, float* __restrict__ hcWr, int NC)
{
    __shared__ float sWlT[1024], sWrT[1024], sAT[512], sBT[512], sWu[80], sbu[16], sbl[32];
    __shared__ float part[256];
    __shared__ float agg[32], hc[32];
    int t = threadIdx.x;
    for (int i = t; i < 1024; i += 256){ int o = i >> 5, k = i & 31; sWlT[k * 32 + o] = Wl[i]; sWrT[k * 32 + o] = Wr[i]; }
    for (int i = t; i < 512;  i += 256){ int j = i >> 5, o = i & 31; sAT[o * 16 + j] = Acoef[i]; sBT[o * 16 + j] = Bcoef[i]; }
    if (t < 80) sWu[t] = Wu[t];
    if (t < 16) sbu[t] = bu[t];
    if (t < 32) sbl[t] = bl[t];
    __syncthreads();
    int el = t >> 5, f = t & 31;   // 8 edge-lanes x 32 features
    for (int c = blockIdx.x; c < NC; c += gridDim.x){
        int lo = off_c[c], hi = off_c[c + 1];
        float acc = 0.f;
        for (int j = lo + el; j < hi; j += 8){
            int s = csr_c[j];
            float v;
            if (f < 16){ v = uemb[uidx[s] * 16 + f]; }
            else {
                int o = f - 16; float d = sbu[o];
                #pragma unroll
                for (int k = 0; k < 5; k++) d += ux[s * 5 + k] * sWu[o * 5 + k];
                v = d;
            }
            acc += v;
        }
        part[t] = acc; __syncthreads();
        if (el == 0){
            float s2 = part[f];
            #pragma unroll
            for (int k = 1; k < 8; k++) s2 += part[k * 32 + f];
            agg[f] = s2 / (float)imax(hi - lo, 1);
        }
        __syncthreads();
        if (t < 32){
            float h = sbl[t];
            for (int k = 0; k < 32; k++) h += agg[k] * sWlT[k * 32 + t] + xc[c * 32 + k] * sWrT[k * 32 + t];
            hc[t] = fmaxf(h, 0.f);
        }
        __syncthreads();
        if (t < 16){
            float a = 0.f, b = 0.f;
            for (int o = 0; o < 32; o++){ float h = hc[o]; a += h * sAT[o * 16 + t]; b += h * sBT[o * 16 + t]; }
            hc2r[c * 16 + t] = a; hcWr[c * 16 + t] = b;
        }
        __syncthreads();
    }
}

// ---------------- layer 1 user side: agg(xc) -> hu -> {hu@c2e_Wl.T, hu@c2r_Wr.T} ----------------

__global__ __launch_bounds__(256) void k_user_l1(
    const int* __restrict__ off_u, const int* __restrict__ csr_u,
    const float* __restrict__ xc,
    const float* __restrict__ uemb, const int* __restrict__ uidx,
    const float* __restrict__ ux, const float* __restrict__ Wu, const float* __restrict__ bu,
    const float* __restrict__ Wl, const float* __restrict__ bl, const float* __restrict__ Wr, // c1r
    const float* __restrict__ Acoef /*c2e_Wl*/, const float* __restrict__ Bcoef /*c2r_Wr*/,
    float* __restrict__ hu2e, float* __restrict__ huWr, int NU)
{
    __shared__ float sWlT[1024], sWrT[1024], sAT[512], sBT[512], sWu[80], sbu[16], sbl[32];
    __shared__ float agg[16][33], xu[16][33], hu[16][33];
    int t = threadIdx.x;
    for (int i = t; i < 1024; i += 256){ int o = i >> 5, k = i & 31; sWlT[k * 32 + o] = Wl[i]; sWrT[k * 32 + o] = Wr[i]; }
    for (int i = t; i < 512;  i += 256){ int j = i >> 5, o = i & 31; sAT[o * 16 + j] = Acoef[i]; sBT[o * 16 + j] = Bcoef[i]; }
    if (t < 80) sWu[t] = Wu[t];
    if (t < 16) sbu[t] = bu[t];
    if (t < 32) sbl[t] = bl[t];
    __syncthreads();
    int ul = t >> 4, f = t & 15;   // 16 users/block, 16 lanes each (features f and f+16)
    for (int u0 = blockIdx.x * 16; u0 < NU; u0 += gridDim.x * 16){
        int u = u0 + ul;
        if (u < NU){
            int lo = off_u[u], hi = off_u[u + 1];
            float a0 = 0.f, a1 = 0.f;
            for (int j = lo; j < hi; j++){
                int d = csr_u[j];
                a0 += xc[d * 32 + f]; a1 += xc[d * 32 + 16 + f];
            }
            float inv = 1.f / (float)imax(hi - lo, 1);
            agg[ul][f] = a0 * inv; agg[ul][f + 16] = a1 * inv;
            xu[ul][f] = uemb[uidx[u] * 16 + f];
            float d2 = sbu[f];
            #pragma unroll
            for (int k = 0; k < 5; k++) d2 += ux[u * 5 + k] * sWu[f * 5 + k];
            xu[ul][f + 16] = d2;
        }
        __syncthreads();
        if (u < NU){
            float h0 = sbl[f], h1 = sbl[f + 16];
            for (int k = 0; k < 32; k++){
                float ag = agg[ul][k], xv = xu[ul][k];
                h0 += ag * sWlT[k * 32 + f]      + xv * sWrT[k * 32 + f];
                h1 += ag * sWlT[k * 32 + f + 16] + xv * sWrT[k * 32 + f + 16];
            }
            hu[ul][f] = fmaxf(h0, 0.f); hu[ul][f + 16] = fmaxf(h1, 0.f);
        }
        __syncthreads();
        if (u < NU){
            float a = 0.f, b = 0.f;
            for (int o = 0; o < 32; o++){ float h = hu[ul][o]; a += h * sAT[o * 16 + f]; b += h * sBT[o * 16 + f]; }
            hu2e[u * 16 + f] = a; huWr[u * 16 + f] = b;
        }
        __syncthreads();
    }
}

// ---------------- layer 2 ----------------

__global__ __launch_bounds__(256) void k_course_l2(
    const int* __restrict__ off_c, const int* __restrict__ csr_c,
    const float* __restrict__ hu2e, const float* __restrict__ bl2,
    const float* __restrict__ hcWr, float* __restrict__ oc, int NC)
{
    __shared__ float part[256];
    int t = threadIdx.x; int el = t >> 4, f = t & 15;  // 16 edge-lanes x 16 features
    for (int c = blockIdx.x; c < NC; c += gridDim.x){
        int lo = off_c[c], hi = off_c[c + 1];
        float acc = 0.f;
        for (int j = lo + el; j < hi; j += 16) acc += hu2e[csr_c[j] * 16 + f];
        part[t] = acc; __syncthreads();
        if (el == 0){
            float s = part[f];
            #pragma unroll
            for (int k = 1; k < 16; k++) s += part[k * 16 + f];
            oc[c * 16 + f] = s / (float)imax(hi - lo, 1) + bl2[f] + hcWr[c * 16 + f];
        }
        __syncthreads();
    }
}

__global__ __launch_bounds__(256) void k_user_l2(
    const int* __restrict__ off_u, const int* __restrict__ csr_u,
    const float* __restrict__ hc2r, const float* __restrict__ bl2,
    const float* __restrict__ huWr, float* __restrict__ ou, int NU)
{
    int t = threadIdx.x; int ul = t >> 4, f = t & 15;
    for (int u0 = blockIdx.x * 16; u0 < NU; u0 += gridDim.x * 16){
        int u = u0 + ul;
        if (u >= NU) continue;
        int lo = off_u[u], hi = off_u[u + 1];
        float acc = 0.f;
        for (int j = lo; j < hi; j++) acc += hc2r[csr_u[j] * 16 + f];
        ou[u * 16 + f] = acc / (float)imax(hi - lo, 1) + bl2[f] + huWr[u * 16 + f];
    }
}

// ---------------- decode: dot(ou[ls], oc[ld]) ----------------

__global__ void k_decode(const int* __restrict__ ls, const int* __restrict__ ld,
                         const float* __restrict__ ou, const float* __restrict__ oc,
                         float* __restrict__ out, int L){
    int gt = blockIdx.x * blockDim.x + threadIdx.x;
    int l = gt >> 2, q = gt & 3;
    if (l >= L) return;
    int a = ls[l], b = ld[l];
    float4 va = ((const float4*)(ou + (size_t)a * 16))[q];
    float4 vb = ((const float4*)(oc + (size_t)b * 16))[q];
    float s = va.x * vb.x + va.y * vb.y + va.z * vb.z + va.w * vb.w;
    s += __shfl_xor(s, 1);
    s += __shfl_xor(s, 2);
    if (q == 0) out[l] = s;
}

// ---------------- launcher ----------------

extern "C" void kernel_launch(void* const* d_in, const int* in_sizes, int n_in,
                              void* d_out, int out_size, void* d_ws, size_t ws_size,
                              hipStream_t stream)
{
    const float* user_x       = (const float*)d_in[0];
    const float* course_x     = (const float*)d_in[1];
    const float* user_embed   = (const float*)d_in[2];
    const float* course_embed = (const float*)d_in[3];
    const float* Wu = (const float*)d_in[4];
    const float* bu = (const float*)d_in[5];
    const float* Wc = (const float*)d_in[6];
    const float* bc = (const float*)d_in[7];
    const float* c1e_Wl = (const float*)d_in[8];
    const float* c1e_bl = (const float*)d_in[9];
    const float* c1e_Wr = (const float*)d_in[10];
    const float* c1r_Wl = (const float*)d_in[11];
    const float* c1r_bl = (const float*)d_in[12];
    const float* c1r_Wr = (const float*)d_in[13];
    const float* c2e_Wl = (const float*)d_in[14];
    const float* c2e_bl = (const float*)d_in[15];
    const float* c2e_Wr = (const float*)d_in[16];
    const float* c2r_Wl = (const float*)d_in[17];
    const float* c2r_bl = (const float*)d_in[18];
    const float* c2r_Wr = (const float*)d_in[19];
    const int* uidx      = (const int*)d_in[20];
    const int* cidx      = (const int*)d_in[21];
    const int* edge_src  = (const int*)d_in[22];
    const int* edge_dst  = (const int*)d_in[23];
    const int* label_src = (const int*)d_in[24];
    const int* label_dst = (const int*)d_in[25];
    const int NU = in_sizes[20], NC = in_sizes[21], E = in_sizes[22], L = in_sizes[24];

    char* ws = (char*)d_ws;
    size_t woff = 0;
    auto alloc = [&](size_t bytes) -> char* {
        char* p = ws + woff;
        woff = (woff + bytes + 255) & ~(size_t)255;
        return p;
    };
    int*   off_u = (int*)  alloc((size_t)(NU + 1) * 4);
    int*   cur_u = (int*)  alloc((size_t)NU * 4);
    int*   off_c = (int*)  alloc((size_t)(NC + 1) * 4);
    int*   cur_c = (int*)  alloc((size_t)NC * 4);
    int*   csr_c = (int*)  alloc((size_t)E * 4);
    int*   csr_u = (int*)  alloc((size_t)E * 4);
    float* xc    = (float*)alloc((size_t)NC * 32 * 4);
    float* hc2r  = (float*)alloc((size_t)NC * 16 * 4);
    float* hcWr  = (float*)alloc((size_t)NC * 16 * 4);
    float* hu2e  = (float*)alloc((size_t)NU * 16 * 4);
    float* huWr  = (float*)alloc((size_t)NU * 16 * 4);
    float* occ   = (float*)alloc((size_t)NC * 16 * 4);
    int*   bsum  = (int*)  alloc(4097 * 4);
    float* ou = hu2e;   // alias: hu2e fully consumed by k_course_l2 before k_user_l2 writes ou
    (void)ws_size; (void)n_in; (void)out_size;

    k_zero<<<(NU + 255) / 256, 256, 0, stream>>>(cur_u, NU);
    k_zero<<<(NC + 255) / 256, 256, 0, stream>>>(cur_c, NC);
    k_hist<<<2048, 256, 0, stream>>>(edge_src, edge_dst, cur_u, cur_c, E);
    k_scan_small<<<1, 256, 0, stream>>>(cur_c, off_c, cur_c, NC);
    int nb = (NU + 2047) / 2048;
    k_scan1<<<nb, 256, 0, stream>>>(cur_u, bsum, NU);
    k_scan_small<<<1, 256, 0, stream>>>(bsum, bsum, bsum, nb);
    k_scan3<<<nb, 256, 0, stream>>>(cur_u, bsum, off_u, cur_u, NU, E);
    k_xc<<<(NC * 32 + 255) / 256, 256, 0, stream>>>(course_x, course_embed, cidx, Wc, bc, xc, NC);
    k_scatter<<<2048, 256, 0, stream>>>(edge_src, edge_dst, cur_c, cur_u, csr_c, csr_u, E);
    k_course_l1<<<2048, 256, 0, stream>>>(off_c, csr_c, user_embed, uidx, user_x, Wu, bu,
                                          c1e_Wl, c1e_bl, c1e_Wr, c2r_Wl, c2e_Wr, xc, hc2r, hcWr, NC);
    k_user_l1<<<2048, 256, 0, stream>>>(off_u, csr_u, xc, user_embed, uidx, user_x, Wu, bu,
                                        c1r_Wl, c1r_bl, c1r_Wr, c2e_Wl, c2r_Wr, hu2e, huWr, NU);
    k_course_l2<<<1024, 256, 0, stream>>>(off_c, csr_c, hu2e, c2e_bl, hcWr, occ, NC);
    k_user_l2<<<2048, 256, 0, stream>>>(off_u, csr_u, hc2r, c2r_bl, huWr, ou, NU);
    k_decode<<<(unsigned)(((size_t)L * 4 + 255) / 256), 256, 0, stream>>>(label_src, label_dst, ou, occ, (float*)d_out, L);
}

// Round 2
// 883.485 us; speedup vs baseline: 1.1905x; 1.1905x over previous
//
#include <hip/hip_runtime.h>

#define THREADS 256

static __device__ __forceinline__ int imax(int a, int b){ return a > b ? a : b; }
static __device__ __forceinline__ int imin(int a, int b){ return a < b ? a : b; }

// ---------------- CSR build ----------------

__global__ void k_zero(int* __restrict__ p, int n){
    int i = blockIdx.x * blockDim.x + threadIdx.x;
    if (i < n) p[i] = 0;
}

// 8 edges/thread, block-contiguous: independent fire-and-forget atomics
__global__ void k_hist(const int* __restrict__ es, const int* __restrict__ ed,
                       int* __restrict__ cu, int* __restrict__ cc, int E){
    const int base = blockIdx.x * (THREADS * 8) + threadIdx.x;
    #pragma unroll
    for (int k = 0; k < 8; k++){
        int i = base + k * THREADS;
        if (i < E){ atomicAdd(&cu[es[i]], 1); atomicAdd(&cc[ed[i]], 1); }
    }
}

// single-block exclusive scan; cnt_in may alias off/cur (per-index owner read-before-write)
__global__ void k_scan_small(const int* __restrict__ cnt_in, int* __restrict__ off,
                             int* __restrict__ cur, int n){
    __shared__ int ssum[THREADS];
    int t = threadIdx.x;
    int chunk = (n + THREADS - 1) / THREADS;
    int lo = t * chunk, hi = imin(lo + chunk, n);
    int s = 0;
    for (int i = lo; i < hi; i++) s += cnt_in[i];
    ssum[t] = s; __syncthreads();
    for (int d = 1; d < THREADS; d <<= 1){
        int v = (t >= d) ? ssum[t - d] : 0;
        __syncthreads();
        if (t >= d) ssum[t] += v;
        __syncthreads();
    }
    int base = t ? ssum[t - 1] : 0;
    for (int i = lo; i < hi; i++){
        int c = cnt_in[i];
        off[i] = base; cur[i] = base;
        base += c;
    }
    if (t == THREADS - 1) off[n] = base;
}

__global__ void k_scan1(const int* __restrict__ cnt, int* __restrict__ bsum, int n){
    __shared__ int red[THREADS];
    int t = threadIdx.x;
    int base = blockIdx.x * 2048;
    int s = 0;
    #pragma unroll
    for (int k = 0; k < 8; k++){ int i = base + t * 8 + k; if (i < n) s += cnt[i]; }
    red[t] = s; __syncthreads();
    for (int d = THREADS >> 1; d > 0; d >>= 1){
        if (t < d) red[t] += red[t + d];
        __syncthreads();
    }
    if (t == 0) bsum[blockIdx.x] = red[0];
}

__global__ void k_scan3(const int* __restrict__ cnt, const int* __restrict__ bsum,
                        int* __restrict__ off, int* __restrict__ cur, int n, int total){
    __shared__ int red[THREADS];
    int t = threadIdx.x;
    int base0 = blockIdx.x * 2048;
    int loc[8]; int s = 0;
    #pragma unroll
    for (int k = 0; k < 8; k++){ int i = base0 + t * 8 + k; loc[k] = (i < n) ? cnt[i] : 0; s += loc[k]; }
    red[t] = s; __syncthreads();
    for (int d = 1; d < THREADS; d <<= 1){
        int v = (t >= d) ? red[t - d] : 0;
        __syncthreads();
        if (t >= d) red[t] += v;
        __syncthreads();
    }
    int run = bsum[blockIdx.x] + (t ? red[t - 1] : 0);
    #pragma unroll
    for (int k = 0; k < 8; k++){
        int i = base0 + t * 8 + k;
        if (i < n){ off[i] = run; cur[i] = run; run += loc[k]; }
    }
    if (blockIdx.x == 0 && t == 0) off[n] = total;
}

// 8 edges/thread, 3 phases: loads | 16 independent atomics | 16 independent stores
__global__ void k_scatter(const int* __restrict__ es, const int* __restrict__ ed,
                          int* __restrict__ cur_c, int* __restrict__ cur_u,
                          int* __restrict__ csr_c, int* __restrict__ csr_u, int E){
    const int base = blockIdx.x * (THREADS * 8) + threadIdx.x;
    int s[8], d[8], pc[8], pu[8];
    #pragma unroll
    for (int k = 0; k < 8; k++){
        int i = base + k * THREADS;
        if (i < E){ s[k] = es[i]; d[k] = ed[i]; }
    }
    #pragma unroll
    for (int k = 0; k < 8; k++){
        int i = base + k * THREADS;
        if (i < E){ pc[k] = atomicAdd(&cur_c[d[k]], 1); pu[k] = atomicAdd(&cur_u[s[k]], 1); }
    }
    #pragma unroll
    for (int k = 0; k < 8; k++){
        int i = base + k * THREADS;
        if (i < E){ csr_c[pc[k]] = s[k]; csr_u[pu[k]] = d[k]; }
    }
}

// ---------------- feature fusion (courses only; xu computed on the fly) ----------------

__global__ void k_xc(const float* __restrict__ cx, const float* __restrict__ cemb,
                     const int* __restrict__ cidx, const float* __restrict__ Wc,
                     const float* __restrict__ bc, float* __restrict__ xc, int NC){
    int i = blockIdx.x * blockDim.x + threadIdx.x;
    if (i >= NC * 32) return;
    int c = i >> 5, f = i & 31;
    float v;
    if (f < 16) v = cemb[cidx[c] * 16 + f];
    else { int o = f - 16; v = bc[o] + cx[c * 2 + 0] * Wc[o * 2 + 0] + cx[c * 2 + 1] * Wc[o * 2 + 1]; }
    xc[i] = v;
}

// xu feature value computed on the fly (f<16: embed, f>=16: 5->16 matvec)
static __device__ __forceinline__ float xu_val(int s, int f,
    const float* __restrict__ uemb, const int* __restrict__ uidx,
    const float* __restrict__ ux, const float* __restrict__ sWu,
    const float* __restrict__ sbu)
{
    if (f < 16) return uemb[uidx[s] * 16 + f];
    int o = f - 16; float d = sbu[o];
    #pragma unroll
    for (int k = 0; k < 5; k++) d += ux[s * 5 + k] * sWu[o * 5 + k];
    return d;
}

// ---------------- layer 1 course side: agg(xu) -> hc -> {hc@c2r_Wl.T, hc@c2e_Wr.T} ----------------

__global__ __launch_bounds__(256) void k_course_l1(
    const int* __restrict__ off_c, const int* __restrict__ csr_c,
    const float* __restrict__ uemb, const int* __restrict__ uidx,
    const float* __restrict__ ux, const float* __restrict__ Wu, const float* __restrict__ bu,
    const float* __restrict__ Wl, const float* __restrict__ bl, const float* __restrict__ Wr,
    const float* __restrict__ Acoef /*c2r_Wl*/, const float* __restrict__ Bcoef /*c2e_Wr*/,
    const float* __restrict__ xc,
    float* __restrict__ hc2r, float* __restrict__ hcWr, int NC)
{
    __shared__ float sWlT[1024], sWrT[1024], sAT[512], sBT[512], sWu[80], sbu[16], sbl[32];
    __shared__ float part[256];
    __shared__ float agg[32], hc[32];
    int t = threadIdx.x;
    for (int i = t; i < 1024; i += 256){ int o = i >> 5, k = i & 31; sWlT[k * 32 + o] = Wl[i]; sWrT[k * 32 + o] = Wr[i]; }
    for (int i = t; i < 512;  i += 256){ int j = i >> 5, o = i & 31; sAT[o * 16 + j] = Acoef[i]; sBT[o * 16 + j] = Bcoef[i]; }
    if (t < 80) sWu[t] = Wu[t];
    if (t < 16) sbu[t] = bu[t];
    if (t < 32) sbl[t] = bl[t];
    __syncthreads();
    int el = t >> 5, f = t & 31;   // 8 edge-lanes x 32 features
    for (int c = blockIdx.x; c < NC; c += gridDim.x){
        int lo = off_c[c], hi = off_c[c + 1];
        float acc = 0.f;
        int j = lo + el;
        for (; j + 8 < hi; j += 16){              // 2 independent gather chains
            int s0 = csr_c[j], s1 = csr_c[j + 8];
            acc += xu_val(s0, f, uemb, uidx, ux, sWu, sbu)
                 + xu_val(s1, f, uemb, uidx, ux, sWu, sbu);
        }
        if (j < hi) acc += xu_val(csr_c[j], f, uemb, uidx, ux, sWu, sbu);
        part[t] = acc; __syncthreads();
        if (el == 0){
            float s2 = part[f];
            #pragma unroll
            for (int k = 1; k < 8; k++) s2 += part[k * 32 + f];
            agg[f] = s2 / (float)imax(hi - lo, 1);
        }
        __syncthreads();
        if (t < 32){
            float h = sbl[t];
            for (int k = 0; k < 32; k++) h += agg[k] * sWlT[k * 32 + t] + xc[c * 32 + k] * sWrT[k * 32 + t];
            hc[t] = fmaxf(h, 0.f);
        }
        __syncthreads();
        if (t < 16){
            float a = 0.f, b = 0.f;
            for (int o = 0; o < 32; o++){ float h = hc[o]; a += h * sAT[o * 16 + t]; b += h * sBT[o * 16 + t]; }
            hc2r[c * 16 + t] = a; hcWr[c * 16 + t] = b;
        }
        __syncthreads();
    }
}

// ---------------- fused user side: one csr_u walk does L1 agg(xc) AND L2 agg(hc2r) ----------------
// outputs: hu2e = hu @ c2e_Wl.T (for course L2), ou = mean(hc2r)+c2r_bl+hu@c2r_Wr.T (final)

__global__ __launch_bounds__(256) void k_user_fused(
    const int* __restrict__ off_u, const int* __restrict__ csr_u,
    const float* __restrict__ xc, const float* __restrict__ hc2r,
    const float* __restrict__ uemb, const int* __restrict__ uidx,
    const float* __restrict__ ux, const float* __restrict__ Wu, const float* __restrict__ bu,
    const float* __restrict__ Wl, const float* __restrict__ bl, const float* __restrict__ Wr, // c1r
    const float* __restrict__ Acoef /*c2e_Wl*/, const float* __restrict__ Bcoef /*c2r_Wr*/,
    const float* __restrict__ bl2 /*c2r_bl*/,
    float* __restrict__ hu2e, float* __restrict__ ou, int NU)
{
    __shared__ float sWlT[1024], sWrT[1024], sAT[512], sBT[512], sWu[80], sbu[16], sbl[32], sbl2[16];
    __shared__ float agg[16][33], xu[16][33], hu[16][33];
    int t = threadIdx.x;
    for (int i = t; i < 1024; i += 256){ int o = i >> 5, k = i & 31; sWlT[k * 32 + o] = Wl[i]; sWrT[k * 32 + o] = Wr[i]; }
    for (int i = t; i < 512;  i += 256){ int j = i >> 5, o = i & 31; sAT[o * 16 + j] = Acoef[i]; sBT[o * 16 + j] = Bcoef[i]; }
    if (t < 80) sWu[t] = Wu[t];
    if (t < 16) sbu[t] = bu[t];
    if (t < 32) sbl[t] = bl[t];
    if (t < 16) sbl2[t] = bl2[t];
    __syncthreads();
    int ul = t >> 4, f = t & 15;   // 16 users/block, 16 lanes each
    for (int u0 = blockIdx.x * 16; u0 < NU; u0 += gridDim.x * 16){
        int u = u0 + ul;
        float b0 = 0.f, inv = 1.f;
        if (u < NU){
            int lo = off_u[u], hi = off_u[u + 1];
            float a0 = 0.f, a1 = 0.f;
            int j = lo;
            for (; j + 1 < hi; j += 2){            // 2 independent chains
                int d0 = csr_u[j], d1 = csr_u[j + 1];
                a0 += xc[d0 * 32 + f]      + xc[d1 * 32 + f];
                a1 += xc[d0 * 32 + 16 + f] + xc[d1 * 32 + 16 + f];
                b0 += hc2r[d0 * 16 + f]    + hc2r[d1 * 16 + f];
            }
            if (j < hi){
                int d0 = csr_u[j];
                a0 += xc[d0 * 32 + f]; a1 += xc[d0 * 32 + 16 + f]; b0 += hc2r[d0 * 16 + f];
            }
            inv = 1.f / (float)imax(hi - lo, 1);
            agg[ul][f] = a0 * inv; agg[ul][f + 16] = a1 * inv;
            xu[ul][f] = uemb[uidx[u] * 16 + f];
            float d2 = sbu[f];
            #pragma unroll
            for (int k = 0; k < 5; k++) d2 += ux[u * 5 + k] * sWu[f * 5 + k];
            xu[ul][f + 16] = d2;
        }
        __syncthreads();
        if (u < NU){
            float h0 = sbl[f], h1 = sbl[f + 16];
            for (int k = 0; k < 32; k++){
                float ag = agg[ul][k], xv = xu[ul][k];
                h0 += ag * sWlT[k * 32 + f]      + xv * sWrT[k * 32 + f];
                h1 += ag * sWlT[k * 32 + f + 16] + xv * sWrT[k * 32 + f + 16];
            }
            hu[ul][f] = fmaxf(h0, 0.f); hu[ul][f + 16] = fmaxf(h1, 0.f);
        }
        __syncthreads();
        if (u < NU){
            float a = 0.f, b = 0.f;
            for (int o = 0; o < 32; o++){ float h = hu[ul][o]; a += h * sAT[o * 16 + f]; b += h * sBT[o * 16 + f]; }
            hu2e[u * 16 + f] = a;
            ou[u * 16 + f] = b0 * inv + sbl2[f] + b;
        }
        __syncthreads();
    }
}

// ---------------- layer 2 course side ----------------

__global__ __launch_bounds__(256) void k_course_l2(
    const int* __restrict__ off_c, const int* __restrict__ csr_c,
    const float* __restrict__ hu2e, const float* __restrict__ bl2,
    const float* __restrict__ hcWr, float* __restrict__ oc, int NC)
{
    __shared__ float part[256];
    int t = threadIdx.x; int el = t >> 4, f = t & 15;  // 16 edge-lanes x 16 features
    for (int c = blockIdx.x; c < NC; c += gridDim.x){
        int lo = off_c[c], hi = off_c[c + 1];
        float acc = 0.f;
        int j = lo + el;
        for (; j + 16 < hi; j += 32){              // 2 independent gather chains
            acc += hu2e[csr_c[j] * 16 + f] + hu2e[csr_c[j + 16] * 16 + f];
        }
        if (j < hi) acc += hu2e[csr_c[j] * 16 + f];
        part[t] = acc; __syncthreads();
        if (el == 0){
            float s = part[f];
            #pragma unroll
            for (int k = 1; k < 16; k++) s += part[k * 16 + f];
            oc[c * 16 + f] = s / (float)imax(hi - lo, 1) + bl2[f] + hcWr[c * 16 + f];
        }
        __syncthreads();
    }
}

// ---------------- decode: dot(ou[ls], oc[ld]) ----------------

__global__ void k_decode(const int* __restrict__ ls, const int* __restrict__ ld,
                         const float* __restrict__ ou, const float* __restrict__ oc,
                         float* __restrict__ out, int L){
    int gt = blockIdx.x * blockDim.x + threadIdx.x;
    int l = gt >> 2, q = gt & 3;
    if (l >= L) return;
    int a = ls[l], b = ld[l];
    float4 va = ((const float4*)(ou + (size_t)a * 16))[q];
    float4 vb = ((const float4*)(oc + (size_t)b * 16))[q];
    float s = va.x * vb.x + va.y * vb.y + va.z * vb.z + va.w * vb.w;
    s += __shfl_xor(s, 1);
    s += __shfl_xor(s, 2);
    if (q == 0) out[l] = s;
}

// ---------------- launcher ----------------

extern "C" void kernel_launch(void* const* d_in, const int* in_sizes, int n_in,
                              void* d_out, int out_size, void* d_ws, size_t ws_size,
                              hipStream_t stream)
{
    const float* user_x       = (const float*)d_in[0];
    const float* course_x     = (const float*)d_in[1];
    const float* user_embed   = (const float*)d_in[2];
    const float* course_embed = (const float*)d_in[3];
    const float* Wu = (const float*)d_in[4];
    const float* bu = (const float*)d_in[5];
    const float* Wc = (const float*)d_in[6];
    const float* bc = (const float*)d_in[7];
    const float* c1e_Wl = (const float*)d_in[8];
    const float* c1e_bl = (const float*)d_in[9];
    const float* c1e_Wr = (const float*)d_in[10];
    const float* c1r_Wl = (const float*)d_in[11];
    const float* c1r_bl = (const float*)d_in[12];
    const float* c1r_Wr = (const float*)d_in[13];
    const float* c2e_Wl = (const float*)d_in[14];
    const float* c2e_bl = (const float*)d_in[15];
    const float* c2e_Wr = (const float*)d_in[16];
    const float* c2r_Wl = (const float*)d_in[17];
    const float* c2r_bl = (const float*)d_in[18];
    const float* c2r_Wr = (const float*)d_in[19];
    const int* uidx      = (const int*)d_in[20];
    const int* cidx      = (const int*)d_in[21];
    const int* edge_src  = (const int*)d_in[22];
    const int* edge_dst  = (const int*)d_in[23];
    const int* label_src = (const int*)d_in[24];
    const int* label_dst = (const int*)d_in[25];
    const int NU = in_sizes[20], NC = in_sizes[21], E = in_sizes[22], L = in_sizes[24];

    char* ws = (char*)d_ws;
    size_t woff = 0;
    auto alloc = [&](size_t bytes) -> char* {
        char* p = ws + woff;
        woff = (woff + bytes + 255) & ~(size_t)255;
        return p;
    };
    int*   off_u = (int*)  alloc((size_t)(NU + 1) * 4);
    int*   cur_u = (int*)  alloc((size_t)NU * 4);
    int*   off_c = (int*)  alloc((size_t)(NC + 1) * 4);
    int*   cur_c = (int*)  alloc((size_t)NC * 4);
    int*   csr_c = (int*)  alloc((size_t)E * 4);
    int*   csr_u = (int*)  alloc((size_t)E * 4);
    float* xc    = (float*)alloc((size_t)NC * 32 * 4);
    float* hc2r  = (float*)alloc((size_t)NC * 16 * 4);
    float* hcWr  = (float*)alloc((size_t)NC * 16 * 4);
    float* hu2e  = (float*)alloc((size_t)NU * 16 * 4);
    float* ou    = (float*)alloc((size_t)NU * 16 * 4);
    float* occ   = (float*)alloc((size_t)NC * 16 * 4);
    int*   bsum  = (int*)  alloc(4097 * 4);
    (void)ws_size; (void)n_in; (void)out_size;

    int ebl = (E + 2047) / 2048;  // 8 edges/thread blocks

    k_zero<<<(NU + 255) / 256, 256, 0, stream>>>(cur_u, NU);
    k_zero<<<(NC + 255) / 256, 256, 0, stream>>>(cur_c, NC);
    k_hist<<<ebl, 256, 0, stream>>>(edge_src, edge_dst, cur_u, cur_c, E);
    k_scan_small<<<1, 256, 0, stream>>>(cur_c, off_c, cur_c, NC);
    int nb = (NU + 2047) / 2048;
    k_scan1<<<nb, 256, 0, stream>>>(cur_u, bsum, NU);
    k_scan_small<<<1, 256, 0, stream>>>(bsum, bsum, bsum, nb);
    k_scan3<<<nb, 256, 0, stream>>>(cur_u, bsum, off_u, cur_u, NU, E);
    k_xc<<<(NC * 32 + 255) / 256, 256, 0, stream>>>(course_x, course_embed, cidx, Wc, bc, xc, NC);
    k_scatter<<<ebl, 256, 0, stream>>>(edge_src, edge_dst, cur_c, cur_u, csr_c, csr_u, E);
    k_course_l1<<<2048, 256, 0, stream>>>(off_c, csr_c, user_embed, uidx, user_x, Wu, bu,
                                          c1e_Wl, c1e_bl, c1e_Wr, c2r_Wl, c2e_Wr, xc, hc2r, hcWr, NC);
    k_user_fused<<<2048, 256, 0, stream>>>(off_u, csr_u, xc, hc2r, user_embed, uidx, user_x, Wu, bu,
                                           c1r_Wl, c1r_bl, c1r_Wr, c2e_Wl, c2r_Wr, c2r_bl, hu2e, ou, NU);
    k_course_l2<<<1024, 256, 0, stream>>>(off_c, csr_c, hu2e, c2e_bl, hcWr, occ, NC);
    k_decode<<<(unsigned)(((size_t)L * 4 + 255) / 256), 256, 0, stream>>>(label_src, label_dst, ou, occ, (float*)d_out, L);
}

// Round 3
// 865.756 us; speedup vs baseline: 1.2149x; 1.0205x over previous
//
#include <hip/hip_runtime.h>

#define THREADS 256

static __device__ __forceinline__ int imax(int a, int b){ return a > b ? a : b; }
static __device__ __forceinline__ int imin(int a, int b){ return a < b ? a : b; }

// ---------------- CSR build ----------------

__global__ void k_zero(int* __restrict__ p, int n){
    int i = blockIdx.x * blockDim.x + threadIdx.x;
    if (i < n) p[i] = 0;
}

// 8 edges/thread, block-contiguous: independent fire-and-forget atomics
__global__ void k_hist(const int* __restrict__ es, const int* __restrict__ ed,
                       int* __restrict__ cu, int* __restrict__ cc, int E){
    const int base = blockIdx.x * (THREADS * 8) + threadIdx.x;
    if (base + 7 * THREADS < E){
        #pragma unroll
        for (int k = 0; k < 8; k++){
            int i = base + k * THREADS;
            atomicAdd(&cu[es[i]], 1); atomicAdd(&cc[ed[i]], 1);
        }
    } else {
        #pragma unroll
        for (int k = 0; k < 8; k++){
            int i = base + k * THREADS;
            if (i < E){ atomicAdd(&cu[es[i]], 1); atomicAdd(&cc[ed[i]], 1); }
        }
    }
}

// single-block exclusive scan; cnt_in may alias off/cur (per-index owner read-before-write)
__global__ void k_scan_small(const int* __restrict__ cnt_in, int* __restrict__ off,
                             int* __restrict__ cur, int n){
    __shared__ int ssum[THREADS];
    int t = threadIdx.x;
    int chunk = (n + THREADS - 1) / THREADS;
    int lo = t * chunk, hi = imin(lo + chunk, n);
    int s = 0;
    for (int i = lo; i < hi; i++) s += cnt_in[i];
    ssum[t] = s; __syncthreads();
    for (int d = 1; d < THREADS; d <<= 1){
        int v = (t >= d) ? ssum[t - d] : 0;
        __syncthreads();
        if (t >= d) ssum[t] += v;
        __syncthreads();
    }
    int base = t ? ssum[t - 1] : 0;
    for (int i = lo; i < hi; i++){
        int c = cnt_in[i];
        off[i] = base; cur[i] = base;
        base += c;
    }
    if (t == THREADS - 1) off[n] = base;
}

__global__ void k_scan1(const int* __restrict__ cnt, int* __restrict__ bsum, int n){
    __shared__ int red[THREADS];
    int t = threadIdx.x;
    int base = blockIdx.x * 2048;
    int s = 0;
    #pragma unroll
    for (int k = 0; k < 8; k++){ int i = base + t * 8 + k; if (i < n) s += cnt[i]; }
    red[t] = s; __syncthreads();
    for (int d = THREADS >> 1; d > 0; d >>= 1){
        if (t < d) red[t] += red[t + d];
        __syncthreads();
    }
    if (t == 0) bsum[blockIdx.x] = red[0];
}

__global__ void k_scan3(const int* __restrict__ cnt, const int* __restrict__ bsum,
                        int* __restrict__ off, int* __restrict__ cur, int n, int total){
    __shared__ int red[THREADS];
    int t = threadIdx.x;
    int base0 = blockIdx.x * 2048;
    int loc[8]; int s = 0;
    #pragma unroll
    for (int k = 0; k < 8; k++){ int i = base0 + t * 8 + k; loc[k] = (i < n) ? cnt[i] : 0; s += loc[k]; }
    red[t] = s; __syncthreads();
    for (int d = 1; d < THREADS; d <<= 1){
        int v = (t >= d) ? red[t - d] : 0;
        __syncthreads();
        if (t >= d) red[t] += v;
        __syncthreads();
    }
    int run = bsum[blockIdx.x] + (t ? red[t - 1] : 0);
    #pragma unroll
    for (int k = 0; k < 8; k++){
        int i = base0 + t * 8 + k;
        if (i < n){ off[i] = run; cur[i] = run; run += loc[k]; }
    }
    if (blockIdx.x == 0 && t == 0) off[n] = total;
}

// 8 edges/thread, 3 phases: loads | 16 independent atomics | 16 nontemporal stores
__global__ void k_scatter(const int* __restrict__ es, const int* __restrict__ ed,
                          int* __restrict__ cur_c, int* __restrict__ cur_u,
                          int* __restrict__ csr_c, int* __restrict__ csr_u, int E){
    const int base = blockIdx.x * (THREADS * 8) + threadIdx.x;
    int s[8], d[8], pc[8], pu[8];
    if (base + 7 * THREADS < E){
        #pragma unroll
        for (int k = 0; k < 8; k++){ int i = base + k * THREADS; s[k] = es[i]; d[k] = ed[i]; }
        #pragma unroll
        for (int k = 0; k < 8; k++){ pc[k] = atomicAdd(&cur_c[d[k]], 1); pu[k] = atomicAdd(&cur_u[s[k]], 1); }
        #pragma unroll
        for (int k = 0; k < 8; k++){
            __builtin_nontemporal_store(s[k], &csr_c[pc[k]]);
            __builtin_nontemporal_store(d[k], &csr_u[pu[k]]);
        }
    } else {
        #pragma unroll
        for (int k = 0; k < 8; k++){ int i = base + k * THREADS; if (i < E){ s[k] = es[i]; d[k] = ed[i]; } }
        #pragma unroll
        for (int k = 0; k < 8; k++){ int i = base + k * THREADS; if (i < E){ pc[k] = atomicAdd(&cur_c[d[k]], 1); pu[k] = atomicAdd(&cur_u[s[k]], 1); } }
        #pragma unroll
        for (int k = 0; k < 8; k++){
            int i = base + k * THREADS;
            if (i < E){
                __builtin_nontemporal_store(s[k], &csr_c[pc[k]]);
                __builtin_nontemporal_store(d[k], &csr_u[pu[k]]);
            }
        }
    }
}

// ---------------- feature fusion (courses only; xu computed on the fly) ----------------

__global__ void k_xc(const float* __restrict__ cx, const float* __restrict__ cemb,
                     const int* __restrict__ cidx, const float* __restrict__ Wc,
                     const float* __restrict__ bc, float* __restrict__ xc, int NC){
    int i = blockIdx.x * blockDim.x + threadIdx.x;
    if (i >= NC * 32) return;
    int c = i >> 5, f = i & 31;
    float v;
    if (f < 16) v = cemb[cidx[c] * 16 + f];
    else { int o = f - 16; v = bc[o] + cx[c * 2 + 0] * Wc[o * 2 + 0] + cx[c * 2 + 1] * Wc[o * 2 + 1]; }
    xc[i] = v;
}

// ---------------- layer 1 course side ----------------
// linearity: mean(concat(emb, ux@Wu.T+bu)) = concat(mean emb, (mean ux)@Wu.T+bu)
// -> aggregate 21 raw dims per edge (16 embed + 5 raw ux), one matvec per course.

__global__ __launch_bounds__(256) void k_course_l1(
    const int* __restrict__ off_c, const int* __restrict__ csr_c,
    const float* __restrict__ uemb, const int* __restrict__ uidx,
    const float* __restrict__ ux, const float* __restrict__ Wu, const float* __restrict__ bu,
    const float* __restrict__ Wl, const float* __restrict__ bl, const float* __restrict__ Wr,
    const float* __restrict__ Acoef /*c2r_Wl*/, const float* __restrict__ Bcoef /*c2e_Wr*/,
    const float* __restrict__ xc,
    float* __restrict__ hc2r, float* __restrict__ hcWr, int NC)
{
    __shared__ float sWlT[1024], sWrT[1024], sAT[512], sBT[512], sWu[80], sbu[16], sbl[32];
    __shared__ float part[256];
    __shared__ float agg[32], aggx[8], hc[32];
    int t = threadIdx.x;
    for (int i = t; i < 1024; i += 256){ int o = i >> 5, k = i & 31; sWlT[k * 32 + o] = Wl[i]; sWrT[k * 32 + o] = Wr[i]; }
    for (int i = t; i < 512;  i += 256){ int j = i >> 5, o = i & 31; sAT[o * 16 + j] = Acoef[i]; sBT[o * 16 + j] = Bcoef[i]; }
    if (t < 80) sWu[t] = Wu[t];
    if (t < 16) sbu[t] = bu[t];
    if (t < 32) sbl[t] = bl[t];
    __syncthreads();
    int el = t >> 5, f = t & 31;   // 8 edge-lanes x 32 features (21 active in gather)
    for (int c = blockIdx.x; c < NC; c += gridDim.x){
        int lo = off_c[c], hi = off_c[c + 1];
        float acc = 0.f;
        if (f < 21){
            int j = lo + el;
            for (; j + 8 < hi; j += 16){              // 2 independent gather chains
                int s0 = csr_c[j], s1 = csr_c[j + 8];
                float v0, v1;
                if (f < 16){ v0 = uemb[uidx[s0] * 16 + f]; v1 = uemb[uidx[s1] * 16 + f]; }
                else       { v0 = ux[s0 * 5 + (f - 16)];   v1 = ux[s1 * 5 + (f - 16)];   }
                acc += v0 + v1;
            }
            if (j < hi){
                int s0 = csr_c[j];
                acc += (f < 16) ? uemb[uidx[s0] * 16 + f] : ux[s0 * 5 + (f - 16)];
            }
        }
        part[t] = acc; __syncthreads();
        float inv = 1.f / (float)imax(hi - lo, 1);
        if (el == 0 && f < 21){
            float s2 = part[f];
            #pragma unroll
            for (int k = 1; k < 8; k++) s2 += part[k * 32 + f];
            s2 *= inv;
            if (f < 16) agg[f] = s2; else aggx[f - 16] = s2;
        }
        __syncthreads();
        if (t < 16){
            float d = sbu[t];
            #pragma unroll
            for (int k = 0; k < 5; k++) d += aggx[k] * sWu[t * 5 + k];
            agg[16 + t] = d;
        }
        __syncthreads();
        if (t < 32){
            float h = sbl[t];
            for (int k = 0; k < 32; k++) h += agg[k] * sWlT[k * 32 + t] + xc[c * 32 + k] * sWrT[k * 32 + t];
            hc[t] = fmaxf(h, 0.f);
        }
        __syncthreads();
        if (t < 16){
            float a = 0.f, b = 0.f;
            for (int o = 0; o < 32; o++){ float h = hc[o]; a += h * sAT[o * 16 + t]; b += h * sBT[o * 16 + t]; }
            hc2r[c * 16 + t] = a; hcWr[c * 16 + t] = b;
        }
        __syncthreads();
    }
}

// ---------------- fused user side: one csr_u walk does L1 agg(xc) AND L2 agg(hc2r) ----------------
// outputs: hu2e = hu @ c2e_Wl.T (for course L2), ou = mean(hc2r)+c2r_bl+hu@c2r_Wr.T (final)

__global__ __launch_bounds__(256) void k_user_fused(
    const int* __restrict__ off_u, const int* __restrict__ csr_u,
    const float* __restrict__ xc, const float* __restrict__ hc2r,
    const float* __restrict__ uemb, const int* __restrict__ uidx,
    const float* __restrict__ ux, const float* __restrict__ Wu, const float* __restrict__ bu,
    const float* __restrict__ Wl, const float* __restrict__ bl, const float* __restrict__ Wr, // c1r
    const float* __restrict__ Acoef /*c2e_Wl*/, const float* __restrict__ Bcoef /*c2r_Wr*/,
    const float* __restrict__ bl2 /*c2r_bl*/,
    float* __restrict__ hu2e, float* __restrict__ ou, int NU)
{
    __shared__ float sWlT[1024], sWrT[1024], sAT[512], sBT[512], sWu[80], sbu[16], sbl[32], sbl2[16];
    __shared__ float agg[16][33], xu[16][33], hu[16][33];
    int t = threadIdx.x;
    for (int i = t; i < 1024; i += 256){ int o = i >> 5, k = i & 31; sWlT[k * 32 + o] = Wl[i]; sWrT[k * 32 + o] = Wr[i]; }
    for (int i = t; i < 512;  i += 256){ int j = i >> 5, o = i & 31; sAT[o * 16 + j] = Acoef[i]; sBT[o * 16 + j] = Bcoef[i]; }
    if (t < 80) sWu[t] = Wu[t];
    if (t < 16) sbu[t] = bu[t];
    if (t < 32) sbl[t] = bl[t];
    if (t < 16) sbl2[t] = bl2[t];
    __syncthreads();
    int ul = t >> 4, f = t & 15;   // 16 users/block, 16 lanes each
    for (int u0 = blockIdx.x * 16; u0 < NU; u0 += gridDim.x * 16){
        int u = u0 + ul;
        float b0 = 0.f, inv = 1.f;
        if (u < NU){
            int lo = off_u[u], hi = off_u[u + 1];
            float a0 = 0.f, a1 = 0.f;
            int j = lo;
            for (; j + 3 < hi; j += 4){            // 4 independent chains (12 gathers in flight)
                int d0 = csr_u[j], d1 = csr_u[j + 1], d2 = csr_u[j + 2], d3 = csr_u[j + 3];
                a0 += xc[d0 * 32 + f]      + xc[d1 * 32 + f]      + xc[d2 * 32 + f]      + xc[d3 * 32 + f];
                a1 += xc[d0 * 32 + 16 + f] + xc[d1 * 32 + 16 + f] + xc[d2 * 32 + 16 + f] + xc[d3 * 32 + 16 + f];
                b0 += hc2r[d0 * 16 + f]    + hc2r[d1 * 16 + f]    + hc2r[d2 * 16 + f]    + hc2r[d3 * 16 + f];
            }
            for (; j < hi; j++){
                int d0 = csr_u[j];
                a0 += xc[d0 * 32 + f]; a1 += xc[d0 * 32 + 16 + f]; b0 += hc2r[d0 * 16 + f];
            }
            inv = 1.f / (float)imax(hi - lo, 1);
            agg[ul][f] = a0 * inv; agg[ul][f + 16] = a1 * inv;
            xu[ul][f] = uemb[uidx[u] * 16 + f];
            float d2v = sbu[f];
            #pragma unroll
            for (int k = 0; k < 5; k++) d2v += ux[u * 5 + k] * sWu[f * 5 + k];
            xu[ul][f + 16] = d2v;
        }
        __syncthreads();
        if (u < NU){
            float h0 = sbl[f], h1 = sbl[f + 16];
            for (int k = 0; k < 32; k++){
                float ag = agg[ul][k], xv = xu[ul][k];
                h0 += ag * sWlT[k * 32 + f]      + xv * sWrT[k * 32 + f];
                h1 += ag * sWlT[k * 32 + f + 16] + xv * sWrT[k * 32 + f + 16];
            }
            hu[ul][f] = fmaxf(h0, 0.f); hu[ul][f + 16] = fmaxf(h1, 0.f);
        }
        __syncthreads();
        if (u < NU){
            float a = 0.f, b = 0.f;
            for (int o = 0; o < 32; o++){ float h = hu[ul][o]; a += h * sAT[o * 16 + f]; b += h * sBT[o * 16 + f]; }
            hu2e[u * 16 + f] = a;
            ou[u * 16 + f] = b0 * inv + sbl2[f] + b;
        }
        __syncthreads();
    }
}

// ---------------- layer 2 course side ----------------

__global__ __launch_bounds__(256) void k_course_l2(
    const int* __restrict__ off_c, const int* __restrict__ csr_c,
    const float* __restrict__ hu2e, const float* __restrict__ bl2,
    const float* __restrict__ hcWr, float* __restrict__ oc, int NC)
{
    __shared__ float part[256];
    int t = threadIdx.x; int el = t >> 4, f = t & 15;  // 16 edge-lanes x 16 features
    for (int c = blockIdx.x; c < NC; c += gridDim.x){
        int lo = off_c[c], hi = off_c[c + 1];
        float acc = 0.f;
        int j = lo + el;
        for (; j + 48 < hi; j += 64){              // 4 independent gather chains
            acc += hu2e[csr_c[j] * 16 + f] + hu2e[csr_c[j + 16] * 16 + f]
                 + hu2e[csr_c[j + 32] * 16 + f] + hu2e[csr_c[j + 48] * 16 + f];
        }
        for (; j < hi; j += 16) acc += hu2e[csr_c[j] * 16 + f];
        part[t] = acc; __syncthreads();
        if (el == 0){
            float s = part[f];
            #pragma unroll
            for (int k = 1; k < 16; k++) s += part[k * 16 + f];
            oc[c * 16 + f] = s / (float)imax(hi - lo, 1) + bl2[f] + hcWr[c * 16 + f];
        }
        __syncthreads();
    }
}

// ---------------- decode: dot(ou[ls], oc[ld]) ----------------

__global__ void k_decode(const int* __restrict__ ls, const int* __restrict__ ld,
                         const float* __restrict__ ou, const float* __restrict__ oc,
                         float* __restrict__ out, int L){
    int gt = blockIdx.x * blockDim.x + threadIdx.x;
    int l = gt >> 2, q = gt & 3;
    if (l >= L) return;
    int a = ls[l], b = ld[l];
    float4 va = ((const float4*)(ou + (size_t)a * 16))[q];
    float4 vb = ((const float4*)(oc + (size_t)b * 16))[q];
    float s = va.x * vb.x + va.y * vb.y + va.z * vb.z + va.w * vb.w;
    s += __shfl_xor(s, 1);
    s += __shfl_xor(s, 2);
    if (q == 0) out[l] = s;
}

// ---------------- launcher ----------------

extern "C" void kernel_launch(void* const* d_in, const int* in_sizes, int n_in,
                              void* d_out, int out_size, void* d_ws, size_t ws_size,
                              hipStream_t stream)
{
    const float* user_x       = (const float*)d_in[0];
    const float* course_x     = (const float*)d_in[1];
    const float* user_embed   = (const float*)d_in[2];
    const float* course_embed = (const float*)d_in[3];
    const float* Wu = (const float*)d_in[4];
    const float* bu = (const float*)d_in[5];
    const float* Wc = (const float*)d_in[6];
    const float* bc = (const float*)d_in[7];
    const float* c1e_Wl = (const float*)d_in[8];
    const float* c1e_bl = (const float*)d_in[9];
    const float* c1e_Wr = (const float*)d_in[10];
    const float* c1r_Wl = (const float*)d_in[11];
    const float* c1r_bl = (const float*)d_in[12];
    const float* c1r_Wr = (const float*)d_in[13];
    const float* c2e_Wl = (const float*)d_in[14];
    const float* c2e_bl = (const float*)d_in[15];
    const float* c2e_Wr = (const float*)d_in[16];
    const float* c2r_Wl = (const float*)d_in[17];
    const float* c2r_bl = (const float*)d_in[18];
    const float* c2r_Wr = (const float*)d_in[19];
    const int* uidx      = (const int*)d_in[20];
    const int* cidx      = (const int*)d_in[21];
    const int* edge_src  = (const int*)d_in[22];
    const int* edge_dst  = (const int*)d_in[23];
    const int* label_src = (const int*)d_in[24];
    const int* label_dst = (const int*)d_in[25];
    const int NU = in_sizes[20], NC = in_sizes[21], E = in_sizes[22], L = in_sizes[24];

    char* ws = (char*)d_ws;
    size_t woff = 0;
    auto alloc = [&](size_t bytes) -> char* {
        char* p = ws + woff;
        woff = (woff + bytes + 255) & ~(size_t)255;
        return p;
    };
    int*   off_u = (int*)  alloc((size_t)(NU + 1) * 4);
    int*   cur_u = (int*)  alloc((size_t)NU * 4);
    int*   off_c = (int*)  alloc((size_t)(NC + 1) * 4);
    int*   cur_c = (int*)  alloc((size_t)NC * 4);
    int*   csr_c = (int*)  alloc((size_t)E * 4);
    int*   csr_u = (int*)  alloc((size_t)E * 4);
    float* xc    = (float*)alloc((size_t)NC * 32 * 4);
    float* hc2r  = (float*)alloc((size_t)NC * 16 * 4);
    float* hcWr  = (float*)alloc((size_t)NC * 16 * 4);
    float* hu2e  = (float*)alloc((size_t)NU * 16 * 4);
    float* ou    = (float*)alloc((size_t)NU * 16 * 4);
    float* occ   = (float*)alloc((size_t)NC * 16 * 4);
    int*   bsum  = (int*)  alloc(4097 * 4);
    (void)ws_size; (void)n_in; (void)out_size;

    int ebl = (E + 2047) / 2048;  // 8 edges/thread blocks

    k_zero<<<(NU + 255) / 256, 256, 0, stream>>>(cur_u, NU);
    k_zero<<<(NC + 255) / 256, 256, 0, stream>>>(cur_c, NC);
    k_hist<<<ebl, 256, 0, stream>>>(edge_src, edge_dst, cur_u, cur_c, E);
    k_scan_small<<<1, 256, 0, stream>>>(cur_c, off_c, cur_c, NC);
    int nb = (NU + 2047) / 2048;
    k_scan1<<<nb, 256, 0, stream>>>(cur_u, bsum, NU);
    k_scan_small<<<1, 256, 0, stream>>>(bsum, bsum, bsum, nb);
    k_scan3<<<nb, 256, 0, stream>>>(cur_u, bsum, off_u, cur_u, NU, E);
    k_xc<<<(NC * 32 + 255) / 256, 256, 0, stream>>>(course_x, course_embed, cidx, Wc, bc, xc, NC);
    k_scatter<<<ebl, 256, 0, stream>>>(edge_src, edge_dst, cur_c, cur_u, csr_c, csr_u, E);
    k_course_l1<<<2048, 256, 0, stream>>>(off_c, csr_c, user_embed, uidx, user_x, Wu, bu,
                                          c1e_Wl, c1e_bl, c1e_Wr, c2r_Wl, c2e_Wr, xc, hc2r, hcWr, NC);
    k_user_fused<<<2048, 256, 0, stream>>>(off_u, csr_u, xc, hc2r, user_embed, uidx, user_x, Wu, bu,
                                           c1r_Wl, c1r_bl, c1r_Wr, c2e_Wl, c2r_Wr, c2r_bl, hu2e, ou, NU);
    k_course_l2<<<1024, 256, 0, stream>>>(off_c, csr_c, hu2e, c2e_bl, hcWr, occ, NC);
    k_decode<<<(unsigned)(((size_t)L * 4 + 255) / 256), 256, 0, stream>>>(label_src, label_dst, ou, occ, (float*)d_out, L);
}

// Round 4
// 792.470 us; speedup vs baseline: 1.3273x; 1.0925x over previous
//
#include <hip/hip_runtime.h>

#define THREADS 256
#define NPART 8

static __device__ __forceinline__ int imax(int a, int b){ return a > b ? a : b; }
static __device__ __forceinline__ int imin(int a, int b){ return a < b ? a : b; }

// ---------------- CSR build ----------------

__global__ void k_zero(int* __restrict__ p, int n){
    int i = blockIdx.x * blockDim.x + threadIdx.x;
    if (i < n) p[i] = 0;
}

// 8 edges/thread, block-contiguous: independent fire-and-forget atomics
__global__ void k_hist(const int* __restrict__ es, const int* __restrict__ ed,
                       int* __restrict__ cu, int* __restrict__ cc, int E){
    const int base = blockIdx.x * (THREADS * 8) + threadIdx.x;
    if (base + 7 * THREADS < E){
        #pragma unroll
        for (int k = 0; k < 8; k++){
            int i = base + k * THREADS;
            int s = __builtin_nontemporal_load(&es[i]);
            int d = __builtin_nontemporal_load(&ed[i]);
            atomicAdd(&cu[s], 1); atomicAdd(&cc[d], 1);
        }
    } else {
        #pragma unroll
        for (int k = 0; k < 8; k++){
            int i = base + k * THREADS;
            if (i < E){ atomicAdd(&cu[es[i]], 1); atomicAdd(&cc[ed[i]], 1); }
        }
    }
}

// single-block exclusive scan; cnt_in may alias off/cur (per-index owner read-before-write)
__global__ void k_scan_small(const int* __restrict__ cnt_in, int* __restrict__ off,
                             int* __restrict__ cur, int n){
    __shared__ int ssum[THREADS];
    int t = threadIdx.x;
    int chunk = (n + THREADS - 1) / THREADS;
    int lo = t * chunk, hi = imin(lo + chunk, n);
    int s = 0;
    for (int i = lo; i < hi; i++) s += cnt_in[i];
    ssum[t] = s; __syncthreads();
    for (int d = 1; d < THREADS; d <<= 1){
        int v = (t >= d) ? ssum[t - d] : 0;
        __syncthreads();
        if (t >= d) ssum[t] += v;
        __syncthreads();
    }
    int base = t ? ssum[t - 1] : 0;
    for (int i = lo; i < hi; i++){
        int c = cnt_in[i];
        off[i] = base; cur[i] = base;
        base += c;
    }
    if (t == THREADS - 1) off[n] = base;
}

__global__ void k_scan1(const int* __restrict__ cnt, int* __restrict__ bsum, int n){
    __shared__ int red[THREADS];
    int t = threadIdx.x;
    int base = blockIdx.x * 2048;
    int s = 0;
    #pragma unroll
    for (int k = 0; k < 8; k++){ int i = base + t * 8 + k; if (i < n) s += cnt[i]; }
    red[t] = s; __syncthreads();
    for (int d = THREADS >> 1; d > 0; d >>= 1){
        if (t < d) red[t] += red[t + d];
        __syncthreads();
    }
    if (t == 0) bsum[blockIdx.x] = red[0];
}

__global__ void k_scan3(const int* __restrict__ cnt, const int* __restrict__ bsum,
                        int* __restrict__ off, int* __restrict__ cur, int n, int total){
    __shared__ int red[THREADS];
    int t = threadIdx.x;
    int base0 = blockIdx.x * 2048;
    int loc[8]; int s = 0;
    #pragma unroll
    for (int k = 0; k < 8; k++){ int i = base0 + t * 8 + k; loc[k] = (i < n) ? cnt[i] : 0; s += loc[k]; }
    red[t] = s; __syncthreads();
    for (int d = 1; d < THREADS; d <<= 1){
        int v = (t >= d) ? red[t - d] : 0;
        __syncthreads();
        if (t >= d) red[t] += v;
        __syncthreads();
    }
    int run = bsum[blockIdx.x] + (t ? red[t - 1] : 0);
    #pragma unroll
    for (int k = 0; k < 8; k++){
        int i = base0 + t * 8 + k;
        if (i < n){ off[i] = run; cur[i] = run; run += loc[k]; }
    }
    if (blockIdx.x == 0 && t == 0) off[n] = total;
}

// Partitioned scatter: block handles partition p = blockIdx%8 of dst-range (csr_c)
// and src-range (csr_u). Under round-robin dispatch, partition p lives on XCD p,
// so each 1MB CSR region accumulates its ~16 writes/line in ONE L2 before writeback.
// Edge stream is nontemporal so it doesn't evict the hot CSR lines.
__global__ __launch_bounds__(256) void k_scatter(
    const int* __restrict__ es, const int* __restrict__ ed,
    int* __restrict__ cur_c, int* __restrict__ cur_u,
    int* __restrict__ csr_c, int* __restrict__ csr_u,
    int E, float cf, float uf)
{
    const int p = blockIdx.x & (NPART - 1);
    const int base = (blockIdx.x >> 3) * (THREADS * 8) + threadIdx.x;
    int s[8], d[8];
    #pragma unroll
    for (int k = 0; k < 8; k++){
        int i = base + k * THREADS;
        if (i < E){ s[k] = __builtin_nontemporal_load(&es[i]); d[k] = __builtin_nontemporal_load(&ed[i]); }
    }
    #pragma unroll
    for (int k = 0; k < 8; k++){
        int i = base + k * THREADS;
        if (i < E){
            int pd = imin((int)((float)d[k] * cf), NPART - 1);
            if (pd == p) csr_c[atomicAdd(&cur_c[d[k]], 1)] = s[k];
        }
    }
    #pragma unroll
    for (int k = 0; k < 8; k++){
        int i = base + k * THREADS;
        if (i < E){
            int ps = imin((int)((float)s[k] * uf), NPART - 1);
            if (ps == p) csr_u[atomicAdd(&cur_u[s[k]], 1)] = d[k];
        }
    }
}

// ---------------- feature fusion (courses only; xu computed on the fly) ----------------

__global__ void k_xc(const float* __restrict__ cx, const float* __restrict__ cemb,
                     const int* __restrict__ cidx, const float* __restrict__ Wc,
                     const float* __restrict__ bc, float* __restrict__ xc, int NC){
    int i = blockIdx.x * blockDim.x + threadIdx.x;
    if (i >= NC * 32) return;
    int c = i >> 5, f = i & 31;
    float v;
    if (f < 16) v = cemb[cidx[c] * 16 + f];
    else { int o = f - 16; v = bc[o] + cx[c * 2 + 0] * Wc[o * 2 + 0] + cx[c * 2 + 1] * Wc[o * 2 + 1]; }
    xc[i] = v;
}

// ---------------- layer 1 course side ----------------
// linearity: mean(concat(emb, ux@Wu.T+bu)) = concat(mean emb, (mean ux)@Wu.T+bu)
// -> aggregate 21 raw dims per edge (16 embed + 5 raw ux), one matvec per course.

__global__ __launch_bounds__(256) void k_course_l1(
    const int* __restrict__ off_c, const int* __restrict__ csr_c,
    const float* __restrict__ uemb, const int* __restrict__ uidx,
    const float* __restrict__ ux, const float* __restrict__ Wu, const float* __restrict__ bu,
    const float* __restrict__ Wl, const float* __restrict__ bl, const float* __restrict__ Wr,
    const float* __restrict__ Acoef /*c2r_Wl*/, const float* __restrict__ Bcoef /*c2e_Wr*/,
    const float* __restrict__ xc,
    float* __restrict__ hc2r, float* __restrict__ hcWr, int NC)
{
    __shared__ float sWlT[1024], sWrT[1024], sAT[512], sBT[512], sWu[80], sbu[16], sbl[32];
    __shared__ float part[256];
    __shared__ float agg[32], aggx[8], hc[32];
    int t = threadIdx.x;
    for (int i = t; i < 1024; i += 256){ int o = i >> 5, k = i & 31; sWlT[k * 32 + o] = Wl[i]; sWrT[k * 32 + o] = Wr[i]; }
    for (int i = t; i < 512;  i += 256){ int j = i >> 5, o = i & 31; sAT[o * 16 + j] = Acoef[i]; sBT[o * 16 + j] = Bcoef[i]; }
    if (t < 80) sWu[t] = Wu[t];
    if (t < 16) sbu[t] = bu[t];
    if (t < 32) sbl[t] = bl[t];
    __syncthreads();
    int el = t >> 5, f = t & 31;   // 8 edge-lanes x 32 features (21 active in gather)
    for (int c = blockIdx.x; c < NC; c += gridDim.x){
        int lo = off_c[c], hi = off_c[c + 1];
        float acc = 0.f;
        if (f < 21){
            int j = lo + el;
            for (; j + 8 < hi; j += 16){              // 2 independent gather chains
                int s0 = csr_c[j], s1 = csr_c[j + 8];
                float v0, v1;
                if (f < 16){ v0 = uemb[uidx[s0] * 16 + f]; v1 = uemb[uidx[s1] * 16 + f]; }
                else       { v0 = ux[s0 * 5 + (f - 16)];   v1 = ux[s1 * 5 + (f - 16)];   }
                acc += v0 + v1;
            }
            if (j < hi){
                int s0 = csr_c[j];
                acc += (f < 16) ? uemb[uidx[s0] * 16 + f] : ux[s0 * 5 + (f - 16)];
            }
        }
        part[t] = acc; __syncthreads();
        float inv = 1.f / (float)imax(hi - lo, 1);
        if (el == 0 && f < 21){
            float s2 = part[f];
            #pragma unroll
            for (int k = 1; k < 8; k++) s2 += part[k * 32 + f];
            s2 *= inv;
            if (f < 16) agg[f] = s2; else aggx[f - 16] = s2;
        }
        __syncthreads();
        if (t < 16){
            float d = sbu[t];
            #pragma unroll
            for (int k = 0; k < 5; k++) d += aggx[k] * sWu[t * 5 + k];
            agg[16 + t] = d;
        }
        __syncthreads();
        if (t < 32){
            float h = sbl[t];
            for (int k = 0; k < 32; k++) h += agg[k] * sWlT[k * 32 + t] + xc[c * 32 + k] * sWrT[k * 32 + t];
            hc[t] = fmaxf(h, 0.f);
        }
        __syncthreads();
        if (t < 16){
            float a = 0.f, b = 0.f;
            for (int o = 0; o < 32; o++){ float h = hc[o]; a += h * sAT[o * 16 + t]; b += h * sBT[o * 16 + t]; }
            hc2r[c * 16 + t] = a; hcWr[c * 16 + t] = b;
        }
        __syncthreads();
    }
}

// ---------------- fused user side: one csr_u walk does L1 agg(xc) AND L2 agg(hc2r) ----------------
// outputs: hu2e = hu @ c2e_Wl.T (for course L2), ou = mean(hc2r)+c2r_bl+hu@c2r_Wr.T (final)

__global__ __launch_bounds__(256) void k_user_fused(
    const int* __restrict__ off_u, const int* __restrict__ csr_u,
    const float* __restrict__ xc, const float* __restrict__ hc2r,
    const float* __restrict__ uemb, const int* __restrict__ uidx,
    const float* __restrict__ ux, const float* __restrict__ Wu, const float* __restrict__ bu,
    const float* __restrict__ Wl, const float* __restrict__ bl, const float* __restrict__ Wr, // c1r
    const float* __restrict__ Acoef /*c2e_Wl*/, const float* __restrict__ Bcoef /*c2r_Wr*/,
    const float* __restrict__ bl2 /*c2r_bl*/,
    float* __restrict__ hu2e, float* __restrict__ ou, int NU)
{
    __shared__ float sWlT[1024], sWrT[1024], sAT[512], sBT[512], sWu[80], sbu[16], sbl[32], sbl2[16];
    __shared__ float agg[16][33], xu[16][33], hu[16][33];
    int t = threadIdx.x;
    for (int i = t; i < 1024; i += 256){ int o = i >> 5, k = i & 31; sWlT[k * 32 + o] = Wl[i]; sWrT[k * 32 + o] = Wr[i]; }
    for (int i = t; i < 512;  i += 256){ int j = i >> 5, o = i & 31; sAT[o * 16 + j] = Acoef[i]; sBT[o * 16 + j] = Bcoef[i]; }
    if (t < 80) sWu[t] = Wu[t];
    if (t < 16) sbu[t] = bu[t];
    if (t < 32) sbl[t] = bl[t];
    if (t < 16) sbl2[t] = bl2[t];
    __syncthreads();
    int ul = t >> 4, f = t & 15;   // 16 users/block, 16 lanes each
    for (int u0 = blockIdx.x * 16; u0 < NU; u0 += gridDim.x * 16){
        int u = u0 + ul;
        float b0 = 0.f, inv = 1.f;
        if (u < NU){
            int lo = off_u[u], hi = off_u[u + 1];
            float a0 = 0.f, a1 = 0.f;
            int j = lo;
            for (; j + 3 < hi; j += 4){            // 4 independent chains (12 gathers in flight)
                int d0 = csr_u[j], d1 = csr_u[j + 1], d2 = csr_u[j + 2], d3 = csr_u[j + 3];
                a0 += xc[d0 * 32 + f]      + xc[d1 * 32 + f]      + xc[d2 * 32 + f]      + xc[d3 * 32 + f];
                a1 += xc[d0 * 32 + 16 + f] + xc[d1 * 32 + 16 + f] + xc[d2 * 32 + 16 + f] + xc[d3 * 32 + 16 + f];
                b0 += hc2r[d0 * 16 + f]    + hc2r[d1 * 16 + f]    + hc2r[d2 * 16 + f]    + hc2r[d3 * 16 + f];
            }
            for (; j < hi; j++){
                int d0 = csr_u[j];
                a0 += xc[d0 * 32 + f]; a1 += xc[d0 * 32 + 16 + f]; b0 += hc2r[d0 * 16 + f];
            }
            inv = 1.f / (float)imax(hi - lo, 1);
            agg[ul][f] = a0 * inv; agg[ul][f + 16] = a1 * inv;
            xu[ul][f] = uemb[uidx[u] * 16 + f];
            float d2v = sbu[f];
            #pragma unroll
            for (int k = 0; k < 5; k++) d2v += ux[u * 5 + k] * sWu[f * 5 + k];
            xu[ul][f + 16] = d2v;
        }
        __syncthreads();
        if (u < NU){
            float h0 = sbl[f], h1 = sbl[f + 16];
            for (int k = 0; k < 32; k++){
                float ag = agg[ul][k], xv = xu[ul][k];
                h0 += ag * sWlT[k * 32 + f]      + xv * sWrT[k * 32 + f];
                h1 += ag * sWlT[k * 32 + f + 16] + xv * sWrT[k * 32 + f + 16];
            }
            hu[ul][f] = fmaxf(h0, 0.f); hu[ul][f + 16] = fmaxf(h1, 0.f);
        }
        __syncthreads();
        if (u < NU){
            float a = 0.f, b = 0.f;
            for (int o = 0; o < 32; o++){ float h = hu[ul][o]; a += h * sAT[o * 16 + f]; b += h * sBT[o * 16 + f]; }
            hu2e[u * 16 + f] = a;
            ou[u * 16 + f] = b0 * inv + sbl2[f] + b;
        }
        __syncthreads();
    }
}

// ---------------- layer 2 course side ----------------

__global__ __launch_bounds__(256) void k_course_l2(
    const int* __restrict__ off_c, const int* __restrict__ csr_c,
    const float* __restrict__ hu2e, const float* __restrict__ bl2,
    const float* __restrict__ hcWr, float* __restrict__ oc, int NC)
{
    __shared__ float part[256];
    int t = threadIdx.x; int el = t >> 4, f = t & 15;  // 16 edge-lanes x 16 features
    for (int c = blockIdx.x; c < NC; c += gridDim.x){
        int lo = off_c[c], hi = off_c[c + 1];
        float acc = 0.f;
        int j = lo + el;
        for (; j + 48 < hi; j += 64){              // 4 independent gather chains
            acc += hu2e[csr_c[j] * 16 + f] + hu2e[csr_c[j + 16] * 16 + f]
                 + hu2e[csr_c[j + 32] * 16 + f] + hu2e[csr_c[j + 48] * 16 + f];
        }
        for (; j < hi; j += 16) acc += hu2e[csr_c[j] * 16 + f];
        part[t] = acc; __syncthreads();
        if (el == 0){
            float s = part[f];
            #pragma unroll
            for (int k = 1; k < 16; k++) s += part[k * 16 + f];
            oc[c * 16 + f] = s / (float)imax(hi - lo, 1) + bl2[f] + hcWr[c * 16 + f];
        }
        __syncthreads();
    }
}

// ---------------- decode: dot(ou[ls], oc[ld]) ----------------

__global__ void k_decode(const int* __restrict__ ls, const int* __restrict__ ld,
                         const float* __restrict__ ou, const float* __restrict__ oc,
                         float* __restrict__ out, int L){
    int gt = blockIdx.x * blockDim.x + threadIdx.x;
    int l = gt >> 2, q = gt & 3;
    if (l >= L) return;
    int a = ls[l], b = ld[l];
    float4 va = ((const float4*)(ou + (size_t)a * 16))[q];
    float4 vb = ((const float4*)(oc + (size_t)b * 16))[q];
    float s = va.x * vb.x + va.y * vb.y + va.z * vb.z + va.w * vb.w;
    s += __shfl_xor(s, 1);
    s += __shfl_xor(s, 2);
    if (q == 0) out[l] = s;
}

// ---------------- launcher ----------------

extern "C" void kernel_launch(void* const* d_in, const int* in_sizes, int n_in,
                              void* d_out, int out_size, void* d_ws, size_t ws_size,
                              hipStream_t stream)
{
    const float* user_x       = (const float*)d_in[0];
    const float* course_x     = (const float*)d_in[1];
    const float* user_embed   = (const float*)d_in[2];
    const float* course_embed = (const float*)d_in[3];
    const float* Wu = (const float*)d_in[4];
    const float* bu = (const float*)d_in[5];
    const float* Wc = (const float*)d_in[6];
    const float* bc = (const float*)d_in[7];
    const float* c1e_Wl = (const float*)d_in[8];
    const float* c1e_bl = (const float*)d_in[9];
    const float* c1e_Wr = (const float*)d_in[10];
    const float* c1r_Wl = (const float*)d_in[11];
    const float* c1r_bl = (const float*)d_in[12];
    const float* c1r_Wr = (const float*)d_in[13];
    const float* c2e_Wl = (const float*)d_in[14];
    const float* c2e_bl = (const float*)d_in[15];
    const float* c2e_Wr = (const float*)d_in[16];
    const float* c2r_Wl = (const float*)d_in[17];
    const float* c2r_bl = (const float*)d_in[18];
    const float* c2r_Wr = (const float*)d_in[19];
    const int* uidx      = (const int*)d_in[20];
    const int* cidx      = (const int*)d_in[21];
    const int* edge_src  = (const int*)d_in[22];
    const int* edge_dst  = (const int*)d_in[23];
    const int* label_src = (const int*)d_in[24];
    const int* label_dst = (const int*)d_in[25];
    const int NU = in_sizes[20], NC = in_sizes[21], E = in_sizes[22], L = in_sizes[24];

    char* ws = (char*)d_ws;
    size_t woff = 0;
    auto alloc = [&](size_t bytes) -> char* {
        char* p = ws + woff;
        woff = (woff + bytes + 255) & ~(size_t)255;
        return p;
    };
    int*   off_u = (int*)  alloc((size_t)(NU + 1) * 4);
    int*   cur_u = (int*)  alloc((size_t)NU * 4);
    int*   off_c = (int*)  alloc((size_t)(NC + 1) * 4);
    int*   cur_c = (int*)  alloc((size_t)NC * 4);
    int*   csr_c = (int*)  alloc((size_t)E * 4);
    int*   csr_u = (int*)  alloc((size_t)E * 4);
    float* xc    = (float*)alloc((size_t)NC * 32 * 4);
    float* hc2r  = (float*)alloc((size_t)NC * 16 * 4);
    float* hcWr  = (float*)alloc((size_t)NC * 16 * 4);
    float* hu2e  = (float*)alloc((size_t)NU * 16 * 4);
    float* ou    = (float*)alloc((size_t)NU * 16 * 4);
    float* occ   = (float*)alloc((size_t)NC * 16 * 4);
    int*   bsum  = (int*)  alloc(4097 * 4);
    (void)ws_size; (void)n_in; (void)out_size;

    int chunks = (E + 2047) / 2048;  // 8 edges/thread blocks

    k_zero<<<(NU + 255) / 256, 256, 0, stream>>>(cur_u, NU);
    k_zero<<<(NC + 255) / 256, 256, 0, stream>>>(cur_c, NC);
    k_hist<<<chunks, 256, 0, stream>>>(edge_src, edge_dst, cur_u, cur_c, E);
    k_scan_small<<<1, 256, 0, stream>>>(cur_c, off_c, cur_c, NC);
    int nb = (NU + 2047) / 2048;
    k_scan1<<<nb, 256, 0, stream>>>(cur_u, bsum, NU);
    k_scan_small<<<1, 256, 0, stream>>>(bsum, bsum, bsum, nb);
    k_scan3<<<nb, 256, 0, stream>>>(cur_u, bsum, off_u, cur_u, NU, E);
    k_xc<<<(NC * 32 + 255) / 256, 256, 0, stream>>>(course_x, course_embed, cidx, Wc, bc, xc, NC);
    k_scatter<<<chunks * NPART, 256, 0, stream>>>(edge_src, edge_dst, cur_c, cur_u, csr_c, csr_u,
                                                  E, (float)NPART / (float)NC, (float)NPART / (float)NU);
    k_course_l1<<<2048, 256, 0, stream>>>(off_c, csr_c, user_embed, uidx, user_x, Wu, bu,
                                          c1e_Wl, c1e_bl, c1e_Wr, c2r_Wl, c2e_Wr, xc, hc2r, hcWr, NC);
    k_user_fused<<<2048, 256, 0, stream>>>(off_u, csr_u, xc, hc2r, user_embed, uidx, user_x, Wu, bu,
                                           c1r_Wl, c1r_bl, c1r_Wr, c2e_Wl, c2r_Wr, c2r_bl, hu2e, ou, NU);
    k_course_l2<<<1024, 256, 0, stream>>>(off_c, csr_c, hu2e, c2e_bl, hcWr, occ, NC);
    k_decode<<<(unsigned)(((size_t)L * 4 + 255) / 256), 256, 0, stream>>>(label_src, label_dst, ou, occ, (float*)d_out, L);
}